// Round 8
// baseline (6402.188 us; speedup 1.0000x reference)
//
#include <hip/hip_runtime.h>
#include <stdint.h>

#define V 4096
#define D 128
#define E 12288
#define NPAD 16384
#define HALF 8192
#define TARGET 2048
#define MAXM (V - TARGET)    // 2048 max merges
#define LCAP 128             // list capacity (entries, u16) -- avg degree ~6
#define CAP 16               // max candidates per round
#define QCAP 1024            // fixup queue

// s_waitcnt imm (gfx9): vmcnt(0) only
#define WAIT_VM0 0x0F70

// ws layout (bytes)
#define WS_BM     0u                               // V*V bits = 2 MB dedupe bitmap
#define WS_LISTS  (V * (V / 8u))                   // V*LCAP*2 = 1 MB
#define WS_LEN    (WS_LISTS + V * LCAP * 2u)       // V u32
#define WS_PRI    (WS_LEN + V * 4u)                // V float
#define WS_KEYS   (WS_PRI + V * 4u)                // NPAD u64
#define WS_PK     (WS_KEYS + NPAD * 8u)            // E u32
#define WS_PAIRS  (WS_PK + E * 4u)                 // MAXM u32
#define WS_MCOUNT (WS_PAIRS + MAXM * 4u)           // 1 int
#define WS_ALIVE  (WS_MCOUNT + 16u)                // V u8

__device__ __forceinline__ unsigned getf(const uint4& r, int c) {
    unsigned lo = (c & 2) ? r.z : r.x;
    unsigned hi = (c & 2) ? r.w : r.y;
    return (c & 1) ? hi : lo;
}

// build adjacency lists; bitmap dedupes duplicate input edges (ref .set is idempotent)
__global__ void k_build(const int* __restrict__ edges, unsigned* __restrict__ bm,
                        unsigned* __restrict__ lenG, unsigned short* __restrict__ lists) {
    int e = blockIdx.x * 256 + threadIdx.x;
    if (e < E) {
        int a = edges[e], b = edges[E + e];
        unsigned o1 = atomicOr(&bm[(a << 7) + (b >> 5)], 1u << (b & 31));
        if (!((o1 >> (b & 31)) & 1u)) {
            unsigned ia = atomicAdd(&lenG[a], 1u);
            if (ia < LCAP) lists[a * LCAP + ia] = (unsigned short)((b << 2) | 2);
        }
        unsigned o2 = atomicOr(&bm[(b << 7) + (a >> 5)], 1u << (a & 31));
        if (!((o2 >> (a & 31)) & 1u)) {
            unsigned ib = atomicAdd(&lenG[b], 1u);
            if (ib < LCAP) lists[b * LCAP + ib] = (unsigned short)((a << 2) | 2);
        }
    }
}

// numpy pairwise f32 sum for n=128 (matches np oracle reduction order)
__global__ void k_pri(const float* __restrict__ f, float* __restrict__ pri) {
    int v = blockIdx.x * 256 + threadIdx.x;
    if (v < V) {
        const float* p = f + v * D;
        float r[8];
#pragma unroll
        for (int j = 0; j < 8; j++) r[j] = __fmul_rn(p[j], p[j]);
        for (int i = 8; i < D; i += 8) {
#pragma unroll
            for (int j = 0; j < 8; j++)
                r[j] = __fadd_rn(r[j], __fmul_rn(p[i + j], p[i + j]));
        }
        float s01 = __fadd_rn(r[0], r[1]);
        float s23 = __fadd_rn(r[2], r[3]);
        float s45 = __fadd_rn(r[4], r[5]);
        float s67 = __fadd_rn(r[6], r[7]);
        pri[v] = __fadd_rn(__fadd_rn(s01, s23), __fadd_rn(s45, s67));
    }
}

__global__ void k_keys(const int* __restrict__ edges, const float* __restrict__ pri,
                       unsigned long long* __restrict__ keys) {
    int s = blockIdx.x * 256 + threadIdx.x;
    if (s < NPAD) {
        unsigned long long rec;
        if (s < E) {
            int a = edges[s], b = edges[E + s];
            float k = __fadd_rn(pri[a], pri[b]);   // epri >= 0 -> bits monotone
            rec = ((unsigned long long)__float_as_uint(k) << 32) | (unsigned)s;
        } else {
            rec = (0xFFFFFFFFull << 32) | (unsigned)s;
        }
        keys[s] = rec;
    }
}

__launch_bounds__(1024)
__global__ void k_sort2(unsigned long long* __restrict__ keys) {
    __shared__ unsigned long long srt[HALF];
    const int tid = threadIdx.x;
    unsigned long long* base = keys + blockIdx.x * HALF;
    for (int s = tid; s < HALF; s += 1024) srt[s] = base[s];
    __syncthreads();
    for (int k = 2; k <= HALF; k <<= 1) {
        for (int j = k >> 1; j >= 1; j >>= 1) {
            for (int i = tid; i < HALF; i += 1024) {
                int ixj = i ^ j;
                if (ixj > i) {
                    unsigned long long x = srt[i], y = srt[ixj];
                    bool up = ((i & k) == 0);
                    if ((x > y) == up) { srt[i] = y; srt[ixj] = x; }
                }
            }
            __syncthreads();
        }
    }
    for (int s = tid; s < HALF; s += 1024) base[s] = srt[s];
}

__launch_bounds__(64)
__global__ void k_mergepath(const unsigned long long* __restrict__ keys,
                            const int* __restrict__ edges, unsigned* __restrict__ pkG) {
    int t = blockIdx.x * 64 + threadIdx.x;
    if (t >= E / 64) return;
    const unsigned long long* A = keys;
    const unsigned long long* B = keys + HALF;
    int d = t * 64;
    int lo = d > HALF ? d - HALF : 0;
    int hi = d < HALF ? d : HALF;
    while (lo < hi) {
        int mid = (lo + hi) >> 1;
        if (A[mid] < B[d - 1 - mid]) lo = mid + 1; else hi = mid;
    }
    int ia = lo, ib = d - lo;
    for (int o = d; o < d + 64; o++) {
        bool takeA = (ib >= HALF) || (ia < HALF && A[ia] < B[ib]);
        unsigned long long r = takeA ? A[ia++] : B[ib++];
        int e = (int)(r & 0xFFFFFFFFull);
        int a = edges[e], b = edges[E + e];
        pkG[o] = ((unsigned)a << 16) | (unsigned)b;
    }
}

// ONE wave: adjacency-list greedy collapse.
// Per round: re-search (monotone) -> endpoint-prefix select (map1 atomicMin) ->
// stage lists -> S-set ownership (map1) -> apply kept merges (map2 ra-test) ->
// fixups (unique x per lane) -> resets (from immutable staged ids).
__launch_bounds__(64, 1)
__global__ void k_collapse(const unsigned* __restrict__ pkG, const unsigned* __restrict__ lenG,
                           unsigned short* lists, unsigned* __restrict__ pairsG,
                           int* __restrict__ mcountG, uint8_t* __restrict__ aliveG,
                           float* __restrict__ out) {
    __shared__ unsigned short shLen[V];          // 8 KB
    __shared__ uint8_t  alive[V];                // 4 KB
    __shared__ unsigned map1[V];                 // 16 KB (min-owner map)
    __shared__ unsigned map2[V];                 // 16 KB (ra membership bitmask)
    __shared__ unsigned stag[2 * CAP * (LCAP / 2)];  // 8 KB staged lists
    __shared__ unsigned shCand[CAP];
    __shared__ unsigned short shOldLen[2 * CAP];
    __shared__ unsigned short shQ[QCAP];         // 2 KB fixup queue
    __shared__ int shQn;
    const int lane = threadIdx.x;
    unsigned short* stag16 = (unsigned short*)stag;

    for (int v = lane; v < V; v += 64) {
        unsigned l = lenG[v];
        shLen[v] = (unsigned short)(l > LCAP ? LCAP : l);
        alive[v] = 1;
        map1[v] = 0xFFFFFFFFu;
        map2[v] = 0u;
    }
    __syncthreads();

    int cnt = V, mcount = 0;
    bool done = false;

    for (int w = 0; w < E && !done; w += 64) {
        unsigned pkv = pkG[w + lane];
        const int a = (int)(pkv >> 16), b = (int)(pkv & 0xFFFFu);
        bool dec = false;

        while (!done) {
            __builtin_amdgcn_s_waitcnt(WAIT_VM0);    // prior round's list stores visible
            // SEARCH: find b in a's list (monotone: 3 or dead endpoint is final)
            bool flag = false;
            if (!dec) {
                if (!alive[a] || !alive[b]) dec = true;
                else {
                    unsigned fv = 0u;
                    int la = shLen[a];
                    const uint4* pl = (const uint4*)(lists + (size_t)a * LCAP);
                    for (int i0 = 0; i0 < la && !fv; i0 += 8) {
                        uint4 c = pl[i0 >> 3];
#pragma unroll
                        for (int t = 0; t < 4; t++) {
                            unsigned wv = getf(c, t);
                            int n0 = i0 + 2 * t;
                            if (n0 < la && (int)((wv & 0xFFFFu) >> 2) == b) fv = wv & 3u;
                            if (n0 + 1 < la && (int)(wv >> 18) == b) fv = (wv >> 16) & 3u;
                        }
                    }
                    if (fv == 2u) flag = true; else dec = true;   // fv==0 safety: reject
                }
            }
            unsigned long long mF = __ballot(flag);
            if (!mF) break;
            int limit = cnt - TARGET; if (limit > CAP) limit = CAP;

            // PHASE A: endpoint-prefix selection (min flagged lane owns endpoints)
            if (flag) { atomicMin(&map1[a], (unsigned)lane); atomicMin(&map1[b], (unsigned)lane); }
            __syncthreads();
            bool sel = flag && (map1[a] == (unsigned)lane) && (map1[b] == (unsigned)lane);
            if (flag) { map1[a] = 0xFFFFFFFFu; map1[b] = 0xFFFFFFFFu; }  // in-wave order: after reads
            unsigned long long mS = __ballot(sel);
            int rank = (int)__popcll(mS & ((1ull << lane) - 1ull));
            int ncand = (int)__popcll(mS); if (ncand > CAP) ncand = CAP;
            bool cand = sel && (rank < CAP);
            if (cand) shCand[rank] = pkv;
            __syncthreads();

            // STAGE: 4 lanes per candidate copy both lists into LDS
            {
                int g = lane >> 2, sub = lane & 3;
                if (g < ncand) {
                    unsigned cp = shCand[g];
                    int v0 = (int)(cp >> 16), v1 = (int)(cp & 0xFFFFu);
                    if (sub == 0) { shOldLen[2 * g] = shLen[v0]; shOldLen[2 * g + 1] = shLen[v1]; }
                    const uint4* p0 = (const uint4*)(lists + (size_t)v0 * LCAP);
                    const uint4* p1 = (const uint4*)(lists + (size_t)v1 * LCAP);
                    uint4* s0 = (uint4*)(stag + (2 * g) * (LCAP / 2));
                    uint4* s1 = (uint4*)(stag + (2 * g + 1) * (LCAP / 2));
                    int l0 = shLen[v0], l1 = shLen[v1];
#pragma unroll
                    for (int t = 0; t < 4; t++) {
                        int wi = sub * 4 + t;
                        if (wi * 8 < l0) s0[wi] = p0[wi];
                        if (wi * 8 < l1) s1[wi] = p1[wi];
                    }
                }
            }
            __syncthreads();

            // PHASE B: S-set ownership, S = {v0,v1} ∪ N(v1)
            {
                int g = lane >> 2, sub = lane & 3;
                if (g < ncand) {
                    unsigned cp = shCand[g];
                    int v0 = (int)(cp >> 16), v1 = (int)(cp & 0xFFFFu);
                    if (sub == 0) { atomicMin(&map1[v0], (unsigned)g); atomicMin(&map1[v1], (unsigned)g); }
                    int l1 = shOldLen[2 * g + 1];
                    for (int j = sub; j < l1; j += 4) {
                        int x = (int)(stag16[(2 * g + 1) * LCAP + j] >> 2);
                        if (x != v0) atomicMin(&map1[x], (unsigned)g);
                    }
                }
            }
            __syncthreads();
            // KEEP: kept iff candidate owns its whole S (exact write/read disjointness)
            bool own = true;
            {
                int g = lane >> 2, sub = lane & 3;
                if (g < ncand) {
                    unsigned cp = shCand[g];
                    int v0 = (int)(cp >> 16), v1 = (int)(cp & 0xFFFFu);
                    if (sub == 0) own = (map1[v0] == (unsigned)g) && (map1[v1] == (unsigned)g);
                    int l1 = shOldLen[2 * g + 1];
                    for (int j = sub; j < l1; j += 4) {
                        int x = (int)(stag16[(2 * g + 1) * LCAP + j] >> 2);
                        if (x != v0 && map1[x] != (unsigned)g) own = false;
                    }
                }
            }
            unsigned long long mN = __ballot(!own);
            unsigned keptBits = 0u; int nk = 0;
            for (int g2 = 0; g2 < ncand; g2++) {
                if (((mN >> (4 * g2)) & 0xFull) == 0ull && nk < limit) {
                    keptBits |= 1u << g2; nk++;
                }
            }
            if (cand && ((keptBits >> rank) & 1u)) dec = true;
            if (lane == 0) shQn = 0;

            // APPLY: one lane per kept merge (lists are ~6-12 entries)
            if (lane < ncand && ((keptBits >> lane) & 1u)) {
                unsigned cp = shCand[lane];
                int v0 = (int)(cp >> 16), v1 = (int)(cp & 0xFFFFu);
                int la = shOldLen[2 * lane], lb = shOldLen[2 * lane + 1];
                const unsigned short* ra = stag16 + (2 * lane) * LCAP;
                const unsigned short* rb = stag16 + (2 * lane + 1) * LCAP;
                for (int i = 0; i < la; i++) {
                    int id = (int)(ra[i] >> 2);
                    if (id != v1) atomicOr(&map2[id], 1u << lane);
                }
                unsigned short* outp = lists + (size_t)v0 * LCAP;
                int wn = 0;
                for (int i = 0; i < la; i++) {
                    unsigned e = ra[i];
                    int id = (int)(e >> 2);
                    if (id == v1) continue;
                    // id in rb  <=>  map1[id]==lane (kept owns all of S exactly)
                    unsigned val = (map1[id] == (unsigned)lane) ? 3u : (e & 3u);
                    outp[wn++] = (unsigned short)((id << 2) | val);
                }
                for (int j = 0; j < lb; j++) {
                    unsigned e = rb[j];
                    int id = (int)(e >> 2);
                    if (id == v0) continue;
                    int qi = atomicAdd(&shQn, 1);
                    if (qi < QCAP) shQ[qi] = (unsigned short)((lane << 8) | j);
                    if ((map2[id] >> lane) & 1u) continue;   // already emitted clamped
                    if (wn < LCAP) outp[wn++] = (unsigned short)e;
                }
                shLen[v0] = (unsigned short)wn;
                alive[v1] = 0;
                int r = __popc(keptBits & ((1u << lane) - 1u));
                pairsG[mcount + r] = cp;
            }
            mcount += nk; cnt -= nk;
            __syncthreads();

            // FIXUPS: each tuple x unique (S-disjoint kept) -> race-free RMW per lane
            int qn = shQn; if (qn > QCAP) qn = QCAP;
            for (int t = lane; t < qn; t += 64) {
                unsigned q = shQ[t];
                int k = (int)(q >> 8), j = (int)(q & 0xFFu);
                unsigned cp = shCand[k];
                int v0 = (int)(cp >> 16), v1 = (int)(cp & 0xFFFFu);
                unsigned e = stag16[(2 * k + 1) * LCAP + j];
                int x = (int)(e >> 2);
                unsigned short* px = lists + (size_t)x * LCAP;
                int lx = shLen[x];
                int p0 = -1, p1 = -1;
                const uint4* pxv = (const uint4*)px;
                for (int i0 = 0; i0 < lx; i0 += 8) {
                    uint4 c = pxv[i0 >> 3];
#pragma unroll
                    for (int tt = 0; tt < 4; tt++) {
                        unsigned wv = getf(c, tt);
                        int n0 = i0 + 2 * tt;
                        int id0 = (int)((wv & 0xFFFFu) >> 2);
                        int id1 = (int)(wv >> 18);
                        if (n0 < lx) { if (id0 == v1) p1 = n0; else if (id0 == v0) p0 = n0; }
                        if (n0 + 1 < lx) { if (id1 == v1) p1 = n0 + 1; else if (id1 == v0) p0 = n0 + 1; }
                    }
                }
                if (p1 >= 0) {
                    if (p0 >= 0) {        // x adj to both: clamp v0 entry, remove v1 entry
                        int last = lx - 1;
                        unsigned short lastv = (p0 == last)
                            ? (unsigned short)((v0 << 2) | 3u) : px[last];
                        px[p0] = (unsigned short)((v0 << 2) | 3u);
                        if (p1 != last) px[p1] = lastv;
                        shLen[x] = (unsigned short)(lx - 1);
                    } else {              // replace v1 -> v0, value carried (symmetry)
                        px[p1] = (unsigned short)((v0 << 2) | (unsigned)(e & 3u));
                    }
                }
            }
            __syncthreads();

            // RESETS from immutable staged ids (consistent with phase-B writes)
            {
                int g = lane >> 2, sub = lane & 3;
                if (g < ncand) {
                    unsigned cp = shCand[g];
                    int v0 = (int)(cp >> 16), v1 = (int)(cp & 0xFFFFu);
                    if (sub == 0) { map1[v0] = 0xFFFFFFFFu; map1[v1] = 0xFFFFFFFFu; }
                    int l1 = shOldLen[2 * g + 1];
                    for (int j = sub; j < l1; j += 4) {
                        int x = (int)(stag16[(2 * g + 1) * LCAP + j] >> 2);
                        if (x != v0) map1[x] = 0xFFFFFFFFu;
                    }
                    if ((keptBits >> g) & 1u) {
                        int l0 = shOldLen[2 * g];
                        for (int i = sub; i < l0; i += 4) {
                            int id = (int)(stag16[(2 * g) * LCAP + i] >> 2);
                            map2[id] = 0u;   // all bits stale post-fixups
                        }
                    }
                }
            }
            if (cnt == TARGET) done = true;
            __syncthreads();
        }
    }

    for (int v = lane; v < V; v += 64) {
        uint8_t ao = alive[v];
        aliveG[v] = ao;
        out[V * D + v] = ao ? 1.0f : 0.0f;
    }
    if (lane == 0) { mcountG[0] = mcount; out[V * D + V] = (float)cnt; }
}

// Replay merge forest: per-vertex (root, weight) then scatter-add w*f[v] into out[root].
__launch_bounds__(256)
__global__ void k_apply(const float* __restrict__ f, const unsigned* __restrict__ pairsG,
                        const int* __restrict__ mcountG, float* __restrict__ out) {
    __shared__ unsigned pl[MAXM];
    __shared__ int rootL[256];
    __shared__ float wL[256];
    const int tid = threadIdx.x;
    const int mc = mcountG[0];
    for (int j = tid; j < mc; j += 256) pl[j] = pairsG[j];
    __syncthreads();
    int cur = blockIdx.x * 256 + tid;
    float w = 1.0f;
    for (int j = 0; j < mc; j++) {
        unsigned p = pl[j];
        int v0 = (int)(p >> 16), v1 = (int)(p & 0xFFFFu);
        if (cur == v1) { cur = v0; w *= 0.5f; }
        else if (cur == v0) w *= 0.5f;
    }
    rootL[tid] = cur;
    wL[tid] = w;
    __syncthreads();
    const int sub = tid >> 7;
    const int d = tid & 127;
    for (int s = 0; s < 256; s += 2) {
        int idx = s + sub;
        int vv = blockIdx.x * 256 + idx;
        atomicAdd(&out[rootL[idx] * D + d], wL[idx] * f[vv * D + d]);
    }
}

extern "C" void kernel_launch(void* const* d_in, const int* in_sizes, int n_in,
                              void* d_out, int out_size, void* d_ws, size_t ws_size,
                              hipStream_t stream) {
    (void)in_sizes; (void)n_in; (void)out_size; (void)ws_size;
    const float* features = (const float*)d_in[0];
    const int* edges = (const int*)d_in[1];
    uint8_t* ws = (uint8_t*)d_ws;
    unsigned* bm = (unsigned*)(ws + WS_BM);
    unsigned short* lists = (unsigned short*)(ws + WS_LISTS);
    unsigned* lenG = (unsigned*)(ws + WS_LEN);
    float* pri = (float*)(ws + WS_PRI);
    unsigned long long* keys = (unsigned long long*)(ws + WS_KEYS);
    unsigned* pkG = (unsigned*)(ws + WS_PK);
    unsigned* pairsG = (unsigned*)(ws + WS_PAIRS);
    int* mcountG = (int*)(ws + WS_MCOUNT);
    uint8_t* aliveG = ws + WS_ALIVE;
    float* out = (float*)d_out;

    hipMemsetAsync(bm, 0, (size_t)V * (V / 8), stream);
    hipMemsetAsync(lenG, 0, (size_t)V * 4, stream);
    hipMemsetAsync(out, 0, (size_t)V * D * sizeof(float), stream);
    k_pri<<<(V + 255) / 256, 256, 0, stream>>>(features, pri);
    k_build<<<(E + 255) / 256, 256, 0, stream>>>(edges, bm, lenG, lists);
    k_keys<<<(NPAD + 255) / 256, 256, 0, stream>>>(edges, pri, keys);
    k_sort2<<<2, 1024, 0, stream>>>(keys);
    k_mergepath<<<(E / 64 + 63) / 64, 64, 0, stream>>>(keys, edges, pkG);
    k_collapse<<<1, 64, 0, stream>>>(pkG, lenG, lists, pairsG, mcountG, aliveG, out);
    k_apply<<<V / 256, 256, 0, stream>>>(features, pairsG, mcountG, out);
}